// Round 10
// baseline (523.265 us; speedup 1.0000x reference)
//
#include <hip/hip_runtime.h>

// GraphAttentionLayer v12: B=16, M=2048, F_IN=128, F_OUT=64, ALPHA=0.2
// out = elu( softmax_j( mask(adj, leaky_relu(f1_i + f2_j)) ) @ (h@W) )
// Algebra: h' = ((P @ h) @ W)/den, f1 = h@(W@a1), f2 = h@(W@a2).
//
// v12: remove adj from the MFMA kernel entirely. v5-v11 k_main all ~140-160us;
// the last invariant is the in-loop adj read: 16x128B segments at 8KB stride
// per wave, nt-flagged -> EVERY load is an L2-bypassing ~600-900cy miss.
//  - k_pack: adj(0/1 int32, 256MB) -> 1-bit masks (8MB), perfectly contiguous
//    streaming (thread=128B, wave=8KB, nt). ~45us = the adj-once floor.
//  - k_main: masks L2-resident; block's 64 rows x 2048 bits = 16KB staged to
//    LDS in prologue (stride-68 pad: 2-way banks, 16B-aligned). Token loop
//    has ZERO global traffic except the 8KB/tile hbf stage (L2-hot, v11
//    structure). Score = bit-test instead of c4>0 -> bit-identical numerics.
//  - k_prep unchanged; v11 barrier/staging structure unchanged.
// d_ws: hbf 8MB @0, f1all/f2all @8MB, mask 8MB @16MB.

#define M_     2048
#define FIN_   128
#define F_     64
#define ALPHA_ 0.2f
#define HS_    132     // k_prep LDS h-tile stride (floats)
#define WT_    132     // Tsum row stride (floats)
#define MS_    68      // mask LDS row stride (u32): 16B-aligned, 2-way banks

typedef float  float4_ __attribute__((ext_vector_type(4)));
typedef short  short8  __attribute__((ext_vector_type(8)));
typedef int    int4_   __attribute__((ext_vector_type(4)));
typedef unsigned int u32x4 __attribute__((ext_vector_type(4)));
typedef unsigned short u16;
typedef unsigned int   u32;

// packed f32x2 -> bf16x2 (RNE)
static __device__ __forceinline__ u32 cvtpk(float lo, float hi) {
    u32 r;
    asm("v_cvt_pk_bf16_f32 %0, %1, %2" : "=v"(r) : "v"(lo), "v"(hi));
    return r;
}

// non-temporal 16B load (read-once stream; don't pollute caches)
static __device__ __forceinline__ int4_ ntload4(const int* p) {
    return __builtin_nontemporal_load((const int4_*)p);
}

// ---------------------------------------------------------------------------
// Phase 1: hbf fragment layout: ((b*64 + t)*8 + nt)*64 + l  (16B per entry)
//   lane l of a wave holds B[n = nt*16 + (l&15)][k = (l>>4)*8 .. +7]
// ---------------------------------------------------------------------------
__global__ __launch_bounds__(256, 4) void k_prep(
    const float* __restrict__ h, const float* __restrict__ W,
    const float* __restrict__ a, u16* __restrict__ hbf,
    float* __restrict__ f1all, float* __restrict__ f2all)
{
    __shared__ float a_s[2 * F_];
    __shared__ float wa1[FIN_], wa2[FIN_];
    __shared__ float hs[32 * HS_];

    const int tid = threadIdx.x;
    const u32 bid = blockIdx.x;
    const u32 lg  = (bid & 7) * 128 + (bid >> 3);   // XCD x produces batches 2x,2x+1
    const int b   = lg >> 6;
    const int t   = lg & 63;

    if (tid < 128) a_s[tid] = a[tid];

    // h tile -> regs (coalesced float4)
    const int tok = tid >> 3, f0 = (tid & 7) * 16;
    const float* hp = h + ((size_t)(b * M_ + t * 32 + tok)) * FIN_ + f0;
    float4_ x0 = *(const float4_*)hp;
    float4_ x1 = *(const float4_*)(hp + 4);
    float4_ x2 = *(const float4_*)(hp + 8);
    float4_ x3 = *(const float4_*)(hp + 12);
    __syncthreads();   // a_s ready

    if (tid < FIN_) {
        float s1 = 0.f, s2 = 0.f;
#pragma unroll 8
        for (int n = 0; n < F_; ++n) {
            float wv = W[tid * F_ + n];
            s1 += wv * a_s[n];
            s2 += wv * a_s[F_ + n];
        }
        wa1[tid] = s1;
        wa2[tid] = s2;
    }

    float* hr = hs + tok * HS_ + f0;
    *(float4_*)(hr)      = x0;
    *(float4_*)(hr + 4)  = x1;
    *(float4_*)(hr + 8)  = x2;
    *(float4_*)(hr + 12) = x3;
    __syncthreads();   // hs + wa ready

    // ---- fragment conversion: thread handles lane l for nt0, nt0+1 ----
    {
        const int l = tid & 63, lc = l & 15, q = l >> 4;
        const int nt0 = (tid >> 6) * 2;
        u32x4* ob = (u32x4*)hbf + ((size_t)(b * 64 + t)) * 8 * 64;
#pragma unroll
        for (int ni = 0; ni < 2; ++ni) {
            const int nt = nt0 + ni;
            const float* cp = hs + (q * 8) * HS_ + nt * 16 + lc;
            u32x4 wv;
            wv[0] = cvtpk(cp[0 * HS_], cp[1 * HS_]);
            wv[1] = cvtpk(cp[2 * HS_], cp[3 * HS_]);
            wv[2] = cvtpk(cp[4 * HS_], cp[5 * HS_]);
            wv[3] = cvtpk(cp[6 * HS_], cp[7 * HS_]);
            ob[nt * 64 + l] = wv;
        }
    }

    // ---- f1/f2 per token (same reduction order as v11) ----
    {
        const int r = tid >> 3, k0 = (tid & 7) * 16;
        const float* rp = hs + r * HS_ + k0;
        float s1 = 0.f, s2 = 0.f;
#pragma unroll
        for (int k = 0; k < 16; ++k) {
            s1 += rp[k] * wa1[k0 + k];
            s2 += rp[k] * wa2[k0 + k];
        }
        s1 += __shfl_xor(s1, 1, 64); s2 += __shfl_xor(s2, 1, 64);
        s1 += __shfl_xor(s1, 2, 64); s2 += __shfl_xor(s2, 2, 64);
        s1 += __shfl_xor(s1, 4, 64); s2 += __shfl_xor(s2, 4, 64);
        if ((tid & 7) == 0) {
            f1all[b * M_ + t * 32 + r] = s1;
            f2all[b * M_ + t * 32 + r] = s2;
        }
    }
}

// ---------------------------------------------------------------------------
// Phase 2: adj -> 1-bit masks. Word w covers tokens [w*32, w*32+32) (= one
// k_main tile of one row); bit j = (adj[w*32+j] > 0). Thread = 1 word =
// 128 B contiguous read; wave = 8 KB contiguous. 2.097M words total.
// ---------------------------------------------------------------------------
__global__ __launch_bounds__(256, 4) void k_pack(
    const int* __restrict__ adj, u32* __restrict__ mask)
{
    u32 wi = blockIdx.x * 256 + threadIdx.x;
#pragma unroll
    for (int it = 0; it < 4; ++it, wi += 2048 * 256) {
        const int* ap = adj + (size_t)wi * 32;
        u32 m = 0;
#pragma unroll
        for (int c = 0; c < 8; ++c) {
            int4_ v = ntload4(ap + c * 4);
            m |= (v[0] > 0 ? 1u : 0u) << (c * 4 + 0);
            m |= (v[1] > 0 ? 1u : 0u) << (c * 4 + 1);
            m |= (v[2] > 0 ? 1u : 0u) << (c * 4 + 2);
            m |= (v[3] > 0 ? 1u : 0u) << (c * 4 + 3);
        }
        mask[wi] = m;
    }
}

// ---------------------------------------------------------------------------
// Phase 3: 512 blocks x 256 thr (4 waves x 16 rows = 64 rows). v11 structure;
// adj replaced by LDS-staged mask bits. Zero HBM in the token loop.
// ---------------------------------------------------------------------------
__global__ __launch_bounds__(256, 2) void k_main(
    const u32* __restrict__ mask, const u16* __restrict__ hbf,
    const float* __restrict__ f1all, const float* __restrict__ f2all,
    const float* __restrict__ W, float* __restrict__ out)
{
    __shared__ char  dyn[41984];          // lbuf 16384 | f2s 8192 | mlds 17408
    __shared__ float dens[64];

    u32x4* lbuf = (u32x4*)dyn;            // 2 x 512-entry tile buffers (16 KB)
    float* f2s  = (float*)(dyn + 16384);  // [2048] 8 KB
    u32*   mlds = (u32*)(dyn + 24576);    // [64][MS_] 17408 B
    float* Tsum = (float*)dyn;            // [64][WT_] 33792 B (epilogue alias)

    const int tid  = threadIdx.x;
    const int w    = tid >> 6;
    const int l    = tid & 63;
    const int lc   = l & 15;
    const int quad = l >> 4;

    const u32 bid = blockIdx.x;
    const u32 lg  = (bid & 7) * 64 + (bid >> 3);    // XCD x consumes batches 2x,2x+1
    const int b   = lg >> 5;
    const int i0  = (lg & 31) * 64;

    // stage f2all[b] -> LDS (8 KB)
    {
        const int o = tid * 8;
        float4_ v0 = *(const float4_*)(f2all + b * M_ + o);
        float4_ v1 = *(const float4_*)(f2all + b * M_ + o + 4);
        *(float4_*)(f2s + o)     = v0;
        *(float4_*)(f2s + o + 4) = v1;
    }
    // stage masks for rows i0..i0+63 -> LDS (16 KB contiguous read)
    {
        const u32* mrow = mask + ((size_t)(b * M_ + i0)) * 64;
#pragma unroll
        for (int c = 0; c < 4; ++c) {
            const int gw = c * 1024 + tid * 4;      // word in [0,4096)
            u32x4 v = *(const u32x4*)(mrow + gw);
            *(u32x4*)(mlds + (gw >> 6) * MS_ + (gw & 63)) = v;
        }
    }

    const float f1r = f1all[b * M_ + i0 + w * 16 + lc];
    const u32x4* hbs = (const u32x4*)hbf + (size_t)b * 32768;   // 64*8*64 entries
    const u32* mrd = mlds + (w * 16 + lc) * MS_;
    const int  msh = quad * 8;

    // stage tile 0 -> buf0 (each thread 2x16B, contiguous)
    {
        u32x4 s0 = hbs[tid];
        u32x4 s1 = hbs[256 + tid];
        lbuf[tid]       = s0;
        lbuf[256 + tid] = s1;
    }

    __syncthreads();   // f2s + mlds + buf0 ready (prologue-only full drain)

    float denacc = 0.f;
    float4_ acc[8];
#pragma unroll
    for (int nt = 0; nt < 8; ++nt) acc[nt] = (float4_){0.f, 0.f, 0.f, 0.f};

#define SC(GE, GO, BE, BO, IDX)                                 \
        {                                                       \
            float xe = f1r + (GE); xe = fmaxf(xe, ALPHA_ * xe); \
            float xo = f1r + (GO); xo = fmaxf(xo, ALPHA_ * xo); \
            float ee = (mq & (1u << (BE))) ? __expf(xe) : 0.f;  \
            float eo = (mq & (1u << (BO))) ? __expf(xo) : 0.f;  \
            u32 pk = cvtpk(ee, eo);                             \
            d += __uint_as_float(pk << 16);                     \
            d += __uint_as_float(pk & 0xFFFF0000u);             \
            pw[IDX] = pk;                                       \
        }

// Per tile T:
//  1. issue hbf stage loads for tile T+1 (only VMEM of the iter; SB(0) pins)
//  2. ds_read current buf (8 x b128) + mask word + f2 pair
//  3. scores (bit-test) ; den ; 8 MFMA
//  4. SB(0); ds_write next buf (auto-wait vmcnt(0) = the 2 stage loads,
//     issued ~1 full phase earlier, L2-hot)
//  5. lgkmcnt(0) + raw s_barrier (no vmcnt drain semantics needed)
#define STAGE(T)                                                              \
    {                                                                         \
        const int ts = ((T) < 63) ? (T) + 1 : 63;                             \
        u32x4 s0 = hbs[ts * 512 + tid];                                       \
        u32x4 s1 = hbs[ts * 512 + 256 + tid];                                 \
        __builtin_amdgcn_sched_barrier(0);                                    \
        const u32x4* lc_ = lbuf + ((T) & 1) * 512;                            \
        u32x4 bb[8];                                                          \
        _Pragma("unroll")                                                     \
        for (int nt = 0; nt < 8; ++nt) bb[nt] = lc_[nt * 64 + l];             \
        const u32 mq = mrd[T] >> msh;                                         \
        float4_ g0 = *(const float4_*)(f2s + (T) * 32 + quad * 8);            \
        float4_ g1 = *(const float4_*)(f2s + (T) * 32 + quad * 8 + 4);        \
        u32x4 pw;                                                             \
        float d = 0.f;                                                        \
        SC(g0[0], g0[1], 0, 1, 0)                                             \
        SC(g0[2], g0[3], 2, 3, 1)                                             \
        SC(g1[0], g1[1], 4, 5, 2)                                             \
        SC(g1[2], g1[3], 6, 7, 3)                                             \
        denacc += d;                                                          \
        const short8 af = __builtin_bit_cast(short8, pw);                     \
        _Pragma("unroll")                                                     \
        for (int nt = 0; nt < 8; ++nt)                                        \
            acc[nt] = __builtin_amdgcn_mfma_f32_16x16x32_bf16(                \
                af, __builtin_bit_cast(short8, bb[nt]), acc[nt], 0, 0, 0);    \
        __builtin_amdgcn_sched_barrier(0);                                    \
        u32x4* ln_ = lbuf + (((T) + 1) & 1) * 512;                            \
        ln_[tid]       = s0;                                                  \
        ln_[256 + tid] = s1;                                                  \
        asm volatile("s_waitcnt lgkmcnt(0)" ::: "memory");                    \
        __builtin_amdgcn_s_barrier();                                         \
        __builtin_amdgcn_sched_barrier(0);                                    \
    }

    for (int o2 = 0; o2 < 32; ++o2) {
        STAGE(2 * o2)
        STAGE(2 * o2 + 1)
    }
#undef STAGE
#undef SC

    // ---- denom: reduce over the 4 quads ----
    denacc += __shfl_xor(denacc, 16, 64);
    denacc += __shfl_xor(denacc, 32, 64);
    if (quad == 0) dens[w * 16 + lc] = denacc;
    __syncthreads();   // loop LDS dead; Tsum alias safe

    // ---- T -> LDS (disjoint per wave: wave w owns rows w*16..+15) ----
#pragma unroll
    for (int nt = 0; nt < 8; ++nt)
#pragma unroll
        for (int mm = 0; mm < 4; ++mm)
            Tsum[(w * 16 + quad * 4 + mm) * WT_ + nt * 16 + lc] = acc[nt][mm];
    __syncthreads();

    // ---- epilogue: out = elu( (T @ W_fp32) / den ), 64 rows in 2 passes ----
#pragma unroll
    for (int rr = 0; rr < 2; ++rr) {
        const int r  = (tid >> 3) + rr * 32;
        const int n0 = (tid & 7) * 8;
        const float den  = dens[r];
        const float rden = (den > 0.f) ? (1.f / den) : 0.f;
        float u[8];
#pragma unroll
        for (int nn = 0; nn < 8; ++nn) u[nn] = 0.f;
#pragma unroll 4
        for (int k = 0; k < FIN_; ++k) {
            const float tv = Tsum[r * WT_ + k];
            float4_ wv0 = *(const float4_*)(W + k * F_ + n0);
            float4_ wv1 = *(const float4_*)(W + k * F_ + n0 + 4);
            u[0] += tv * wv0[0]; u[1] += tv * wv0[1];
            u[2] += tv * wv0[2]; u[3] += tv * wv0[3];
            u[4] += tv * wv1[0]; u[5] += tv * wv1[1];
            u[6] += tv * wv1[2]; u[7] += tv * wv1[3];
        }
        float4_ o0, o1;
#pragma unroll
        for (int nn = 0; nn < 8; ++nn) {
            float hp = u[nn] * rden;
            float o  = hp > 0.f ? hp : expm1f(hp);
            if (nn < 4) o0[nn] = o; else o1[nn - 4] = o;
        }
        float* op = out + ((size_t)(b * M_ + i0 + r)) * F_ + n0;
        *(float4_*)op       = o0;
        *(float4_*)(op + 4) = o1;
    }
}

// ---------------------------------------------------------------------------
extern "C" void kernel_launch(void* const* d_in, const int* in_sizes, int n_in,
                              void* d_out, int out_size, void* d_ws, size_t ws_size,
                              hipStream_t stream)
{
    (void)out_size; (void)ws_size;
    const float* h  = (const float*)d_in[0];
    const int* adjp = (const int*)d_in[1];
    const float* Wp = (const float*)d_in[2];
    const float* ap = (const float*)d_in[3];
    for (int i = 0; i < n_in; ++i) {
        long s = in_sizes[i];
        if      (s == 4194304L)  h    = (const float*)d_in[i];
        else if (s == 67108864L) adjp = (const int*)d_in[i];
        else if (s == 8192L)     Wp   = (const float*)d_in[i];
        else if (s == 128L)      ap   = (const float*)d_in[i];
    }
    u16*   hbf   = (u16*)d_ws;                                  // 8 MB
    float* f1all = (float*)((char*)d_ws + (8u << 20));          // 128 KB
    float* f2all = f1all + 16 * M_;                             // 128 KB
    u32*   maskp = (u32*)((char*)d_ws + (16u << 20));           // 8 MB
    k_prep<<<1024, 256, 0, stream>>>(h, Wp, ap, hbf, f1all, f2all);
    k_pack<<<2048, 256, 0, stream>>>(adjp, maskp);
    k_main<<<512, 256, 0, stream>>>(maskp, hbf, f1all, f2all, Wp, (float*)d_out);
}

// Round 11
// 417.593 us; speedup vs baseline: 1.2531x; 1.2531x over previous
//
#include <hip/hip_runtime.h>

// GraphAttentionLayer v13: B=16, M=2048, F_IN=128, F_OUT=64, ALPHA=0.2
// out = elu( softmax_j( mask(adj, leaky_relu(f1_i + f2_j)) ) @ (h@W) )
// Algebra: h' = ((P @ h) @ W)/den, f1 = h@(W@a1), f2 = h@(W@a2).
//
// v13 = v12 with two root-cause fixes:
//  - k_pack was UNCOALESCED (thread-contiguous 128B -> lanes at 128B stride,
//    64 lines/instr, nt no-retention -> ~4x refetch of 256MB = the +106us
//    regression). Now: lane l reads int4 at seg*1024 + l*16 (wave = dense
//    1KB), nibble -> 3x shfl_xor OR -> one mask word per 8 lanes. ~47us.
//  - k_main per-tile chain had stage-load latency INSIDE the tile (loads
//    issued at top, drained by same tile's ds_write). Now: stage REGISTER
//    double-buffer - issue T+2's loads into ping-pong regs (static names),
//    ds_write the regs loaded LAST iter -> auto-wait = counted vmcnt(2)
//    with a full tile of slack; L2 latency off the critical path.
// Decomposition identity: total = kernels + ~262us harness constant.
// prep ~10 + pack ~47 + main X: X<=40 confirms; X~145 refutes -> ablate.

#define M_     2048
#define FIN_   128
#define F_     64
#define ALPHA_ 0.2f
#define HS_    132     // k_prep LDS h-tile stride (floats)
#define WT_    132     // Tsum row stride (floats)
#define MS_    68      // mask LDS row stride (u32): 16B-aligned, 2-way banks

typedef float  float4_ __attribute__((ext_vector_type(4)));
typedef short  short8  __attribute__((ext_vector_type(8)));
typedef int    int4_   __attribute__((ext_vector_type(4)));
typedef unsigned int u32x4 __attribute__((ext_vector_type(4)));
typedef unsigned short u16;
typedef unsigned int   u32;

// packed f32x2 -> bf16x2 (RNE)
static __device__ __forceinline__ u32 cvtpk(float lo, float hi) {
    u32 r;
    asm("v_cvt_pk_bf16_f32 %0, %1, %2" : "=v"(r) : "v"(lo), "v"(hi));
    return r;
}

// non-temporal 16B load (read-once stream; don't pollute caches)
static __device__ __forceinline__ int4_ ntload4(const int* p) {
    return __builtin_nontemporal_load((const int4_*)p);
}

// ---------------------------------------------------------------------------
// Phase 1: hbf fragment layout: ((b*64 + t)*8 + nt)*64 + l  (16B per entry)
//   lane l of a wave holds B[n = nt*16 + (l&15)][k = (l>>4)*8 .. +7]
// ---------------------------------------------------------------------------
__global__ __launch_bounds__(256, 4) void k_prep(
    const float* __restrict__ h, const float* __restrict__ W,
    const float* __restrict__ a, u16* __restrict__ hbf,
    float* __restrict__ f1all, float* __restrict__ f2all)
{
    __shared__ float a_s[2 * F_];
    __shared__ float wa1[FIN_], wa2[FIN_];
    __shared__ float hs[32 * HS_];

    const int tid = threadIdx.x;
    const u32 bid = blockIdx.x;
    const u32 lg  = (bid & 7) * 128 + (bid >> 3);   // XCD x produces batches 2x,2x+1
    const int b   = lg >> 6;
    const int t   = lg & 63;

    if (tid < 128) a_s[tid] = a[tid];

    // h tile -> regs (coalesced float4)
    const int tok = tid >> 3, f0 = (tid & 7) * 16;
    const float* hp = h + ((size_t)(b * M_ + t * 32 + tok)) * FIN_ + f0;
    float4_ x0 = *(const float4_*)hp;
    float4_ x1 = *(const float4_*)(hp + 4);
    float4_ x2 = *(const float4_*)(hp + 8);
    float4_ x3 = *(const float4_*)(hp + 12);
    __syncthreads();   // a_s ready

    if (tid < FIN_) {
        float s1 = 0.f, s2 = 0.f;
#pragma unroll 8
        for (int n = 0; n < F_; ++n) {
            float wv = W[tid * F_ + n];
            s1 += wv * a_s[n];
            s2 += wv * a_s[F_ + n];
        }
        wa1[tid] = s1;
        wa2[tid] = s2;
    }

    float* hr = hs + tok * HS_ + f0;
    *(float4_*)(hr)      = x0;
    *(float4_*)(hr + 4)  = x1;
    *(float4_*)(hr + 8)  = x2;
    *(float4_*)(hr + 12) = x3;
    __syncthreads();   // hs + wa ready

    // ---- fragment conversion: thread handles lane l for nt0, nt0+1 ----
    {
        const int l = tid & 63, lc = l & 15, q = l >> 4;
        const int nt0 = (tid >> 6) * 2;
        u32x4* ob = (u32x4*)hbf + ((size_t)(b * 64 + t)) * 8 * 64;
#pragma unroll
        for (int ni = 0; ni < 2; ++ni) {
            const int nt = nt0 + ni;
            const float* cp = hs + (q * 8) * HS_ + nt * 16 + lc;
            u32x4 wv;
            wv[0] = cvtpk(cp[0 * HS_], cp[1 * HS_]);
            wv[1] = cvtpk(cp[2 * HS_], cp[3 * HS_]);
            wv[2] = cvtpk(cp[4 * HS_], cp[5 * HS_]);
            wv[3] = cvtpk(cp[6 * HS_], cp[7 * HS_]);
            ob[nt * 64 + l] = wv;
        }
    }

    // ---- f1/f2 per token (same reduction order as v12) ----
    {
        const int r = tid >> 3, k0 = (tid & 7) * 16;
        const float* rp = hs + r * HS_ + k0;
        float s1 = 0.f, s2 = 0.f;
#pragma unroll
        for (int k = 0; k < 16; ++k) {
            s1 += rp[k] * wa1[k0 + k];
            s2 += rp[k] * wa2[k0 + k];
        }
        s1 += __shfl_xor(s1, 1, 64); s2 += __shfl_xor(s2, 1, 64);
        s1 += __shfl_xor(s1, 2, 64); s2 += __shfl_xor(s2, 2, 64);
        s1 += __shfl_xor(s1, 4, 64); s2 += __shfl_xor(s2, 4, 64);
        if ((tid & 7) == 0) {
            f1all[b * M_ + t * 32 + r] = s1;
            f2all[b * M_ + t * 32 + r] = s2;
        }
    }
}

// ---------------------------------------------------------------------------
// Phase 2: adj -> 1-bit masks, COALESCED. Segment s = 256 tokens (1 KB).
// Lane l reads int4 at s*1024 + l*16 (wave = dense 1 KB, nt). Lane nibble
// (4 tokens) -> OR-merge across 8-lane groups via shfl_xor -> word k
// (tokens 32k..32k+31) written by lane 8k. 262144 segments total.
// ---------------------------------------------------------------------------
__global__ __launch_bounds__(256, 4) void k_pack(
    const int* __restrict__ adj, u32* __restrict__ mask)
{
    const int l = threadIdx.x & 63;
    u32 s = blockIdx.x * 4 + (threadIdx.x >> 6);   // global wave id, 0..8191
#pragma unroll 4
    for (int it = 0; it < 32; ++it, s += 8192) {
        int4_ v = ntload4(adj + (size_t)s * 256 + l * 4);
        u32 m = ((v[0] > 0 ? 1u : 0u) | (v[1] > 0 ? 2u : 0u)
               | (v[2] > 0 ? 4u : 0u) | (v[3] > 0 ? 8u : 0u)) << ((l & 7) * 4);
        m |= __shfl_xor(m, 1, 64);
        m |= __shfl_xor(m, 2, 64);
        m |= __shfl_xor(m, 4, 64);
        if ((l & 7) == 0) mask[s * 8 + (l >> 3)] = m;
    }
}

// ---------------------------------------------------------------------------
// Phase 3: 512 blocks x 256 thr (4 waves x 16 rows = 64 rows). v12 structure
// + stage-register double-buffer (full-tile vmcnt slack). Zero HBM in loop.
// ---------------------------------------------------------------------------
__global__ __launch_bounds__(256, 2) void k_main(
    const u32* __restrict__ mask, const u16* __restrict__ hbf,
    const float* __restrict__ f1all, const float* __restrict__ f2all,
    const float* __restrict__ W, float* __restrict__ out)
{
    __shared__ char  dyn[41984];          // lbuf 16384 | f2s 8192 | mlds 17408
    __shared__ float dens[64];

    u32x4* lbuf = (u32x4*)dyn;            // 2 x 512-entry tile buffers (16 KB)
    float* f2s  = (float*)(dyn + 16384);  // [2048] 8 KB
    u32*   mlds = (u32*)(dyn + 24576);    // [64][MS_] 17408 B
    float* Tsum = (float*)dyn;            // [64][WT_] 33792 B (epilogue alias)

    const int tid  = threadIdx.x;
    const int w    = tid >> 6;
    const int l    = tid & 63;
    const int lc   = l & 15;
    const int quad = l >> 4;

    const u32 bid = blockIdx.x;
    const u32 lg  = (bid & 7) * 64 + (bid >> 3);    // XCD x consumes batches 2x,2x+1
    const int b   = lg >> 5;
    const int i0  = (lg & 31) * 64;

    // stage f2all[b] -> LDS (8 KB)
    {
        const int o = tid * 8;
        float4_ v0 = *(const float4_*)(f2all + b * M_ + o);
        float4_ v1 = *(const float4_*)(f2all + b * M_ + o + 4);
        *(float4_*)(f2s + o)     = v0;
        *(float4_*)(f2s + o + 4) = v1;
    }
    // stage masks for rows i0..i0+63 -> LDS (16 KB contiguous read)
    {
        const u32* mrow = mask + ((size_t)(b * M_ + i0)) * 64;
#pragma unroll
        for (int c = 0; c < 4; ++c) {
            const int gw = c * 1024 + tid * 4;      // word in [0,4096)
            u32x4 v = *(const u32x4*)(mrow + gw);
            *(u32x4*)(mlds + (gw >> 6) * MS_ + (gw & 63)) = v;
        }
    }

    const float f1r = f1all[b * M_ + i0 + w * 16 + lc];
    const u32x4* hbs = (const u32x4*)hbf + (size_t)b * 32768;   // 64*8*64 entries
    const u32* mrd = mlds + (w * 16 + lc) * MS_;
    const int  msh = quad * 8;

    // prologue: tile 0 -> buf0 (via regs); tile 1 held in sB
    u32x4 sA0, sA1, sB0, sB1;
    sA0 = hbs[tid];
    sA1 = hbs[256 + tid];
    lbuf[tid]       = sA0;
    lbuf[256 + tid] = sA1;
    sB0 = hbs[512 + tid];
    sB1 = hbs[512 + 256 + tid];

    __syncthreads();   // f2s + mlds + buf0 ready (prologue-only full drain)

    float denacc = 0.f;
    float4_ acc[8];
#pragma unroll
    for (int nt = 0; nt < 8; ++nt) acc[nt] = (float4_){0.f, 0.f, 0.f, 0.f};

#define SC(GE, GO, BE, BO, IDX)                                 \
        {                                                       \
            float xe = f1r + (GE); xe = fmaxf(xe, ALPHA_ * xe); \
            float xo = f1r + (GO); xo = fmaxf(xo, ALPHA_ * xo); \
            float ee = (mq & (1u << (BE))) ? __expf(xe) : 0.f;  \
            float eo = (mq & (1u << (BO))) ? __expf(xo) : 0.f;  \
            u32 pk = cvtpk(ee, eo);                             \
            d += __uint_as_float(pk << 16);                     \
            d += __uint_as_float(pk & 0xFFFF0000u);             \
            pw[IDX] = pk;                                       \
        }

// Per tile T:
//  1. issue stage loads for tile T+2 into (L0,L1)   [consumed NEXT iter]
//  2. ds_read current buf + mask word + f2 pair; scores; den; 8 MFMA
//  3. ds_write (W0,W1) = regs loaded LAST iter (tile T+1) -> buf[(T+1)&1]
//     auto-wait = vmcnt(2) (only this iter's 2 loads newer) with a FULL
//     TILE of slack -> L2 latency off the critical path.
//  4. lgkmcnt(0) + raw s_barrier (no vmcnt drain).
// Race check: buf[(T+1)&1] was last read in iter T-1; the T-1 -> T barrier
// ordered those reads before this write.
#define STAGE(T, L0, L1, W0, W1)                                              \
    {                                                                         \
        const int tl = ((T) + 2 < 64) ? (T) + 2 : 63;                         \
        L0 = hbs[tl * 512 + tid];                                             \
        L1 = hbs[tl * 512 + 256 + tid];                                       \
        __builtin_amdgcn_sched_barrier(0);                                    \
        const u32x4* lc_ = lbuf + ((T) & 1) * 512;                            \
        u32x4 bb[8];                                                          \
        _Pragma("unroll")                                                     \
        for (int nt = 0; nt < 8; ++nt) bb[nt] = lc_[nt * 64 + l];             \
        const u32 mq = mrd[T] >> msh;                                         \
        float4_ g0 = *(const float4_*)(f2s + (T) * 32 + quad * 8);            \
        float4_ g1 = *(const float4_*)(f2s + (T) * 32 + quad * 8 + 4);        \
        u32x4 pw;                                                             \
        float d = 0.f;                                                        \
        SC(g0[0], g0[1], 0, 1, 0)                                             \
        SC(g0[2], g0[3], 2, 3, 1)                                             \
        SC(g1[0], g1[1], 4, 5, 2)                                             \
        SC(g1[2], g1[3], 6, 7, 3)                                             \
        denacc += d;                                                          \
        const short8 af = __builtin_bit_cast(short8, pw);                     \
        _Pragma("unroll")                                                     \
        for (int nt = 0; nt < 8; ++nt)                                        \
            acc[nt] = __builtin_amdgcn_mfma_f32_16x16x32_bf16(                \
                af, __builtin_bit_cast(short8, bb[nt]), acc[nt], 0, 0, 0);    \
        __builtin_amdgcn_sched_barrier(0);                                    \
        u32x4* ln_ = lbuf + (((T) + 1) & 1) * 512;                            \
        ln_[tid]       = W0;                                                  \
        ln_[256 + tid] = W1;                                                  \
        asm volatile("s_waitcnt lgkmcnt(0)" ::: "memory");                    \
        __builtin_amdgcn_s_barrier();                                         \
        __builtin_amdgcn_sched_barrier(0);                                    \
    }

    for (int o2 = 0; o2 < 32; ++o2) {
        STAGE(2 * o2,     sA0, sA1, sB0, sB1)   // even T: load sA, write sB
        STAGE(2 * o2 + 1, sB0, sB1, sA0, sA1)   // odd  T: load sB, write sA
    }
#undef STAGE
#undef SC

    // ---- denom: reduce over the 4 quads ----
    denacc += __shfl_xor(denacc, 16, 64);
    denacc += __shfl_xor(denacc, 32, 64);
    if (quad == 0) dens[w * 16 + lc] = denacc;
    __syncthreads();   // loop LDS dead; Tsum alias safe

    // ---- T -> LDS (disjoint per wave: wave w owns rows w*16..+15) ----
#pragma unroll
    for (int nt = 0; nt < 8; ++nt)
#pragma unroll
        for (int mm = 0; mm < 4; ++mm)
            Tsum[(w * 16 + quad * 4 + mm) * WT_ + nt * 16 + lc] = acc[nt][mm];
    __syncthreads();

    // ---- epilogue: out = elu( (T @ W_fp32) / den ), 64 rows in 2 passes ----
#pragma unroll
    for (int rr = 0; rr < 2; ++rr) {
        const int r  = (tid >> 3) + rr * 32;
        const int n0 = (tid & 7) * 8;
        const float den  = dens[r];
        const float rden = (den > 0.f) ? (1.f / den) : 0.f;
        float u[8];
#pragma unroll
        for (int nn = 0; nn < 8; ++nn) u[nn] = 0.f;
#pragma unroll 4
        for (int k = 0; k < FIN_; ++k) {
            const float tv = Tsum[r * WT_ + k];
            float4_ wv0 = *(const float4_*)(W + k * F_ + n0);
            float4_ wv1 = *(const float4_*)(W + k * F_ + n0 + 4);
            u[0] += tv * wv0[0]; u[1] += tv * wv0[1];
            u[2] += tv * wv0[2]; u[3] += tv * wv0[3];
            u[4] += tv * wv1[0]; u[5] += tv * wv1[1];
            u[6] += tv * wv1[2]; u[7] += tv * wv1[3];
        }
        float4_ o0, o1;
#pragma unroll
        for (int nn = 0; nn < 8; ++nn) {
            float hp = u[nn] * rden;
            float o  = hp > 0.f ? hp : expm1f(hp);
            if (nn < 4) o0[nn] = o; else o1[nn - 4] = o;
        }
        float* op = out + ((size_t)(b * M_ + i0 + r)) * F_ + n0;
        *(float4_*)op       = o0;
        *(float4_*)(op + 4) = o1;
    }
}

// ---------------------------------------------------------------------------
extern "C" void kernel_launch(void* const* d_in, const int* in_sizes, int n_in,
                              void* d_out, int out_size, void* d_ws, size_t ws_size,
                              hipStream_t stream)
{
    (void)out_size; (void)ws_size;
    const float* h  = (const float*)d_in[0];
    const int* adjp = (const int*)d_in[1];
    const float* Wp = (const float*)d_in[2];
    const float* ap = (const float*)d_in[3];
    for (int i = 0; i < n_in; ++i) {
        long s = in_sizes[i];
        if      (s == 4194304L)  h    = (const float*)d_in[i];
        else if (s == 67108864L) adjp = (const int*)d_in[i];
        else if (s == 8192L)     Wp   = (const float*)d_in[i];
        else if (s == 128L)      ap   = (const float*)d_in[i];
    }
    u16*   hbf   = (u16*)d_ws;                                  // 8 MB
    float* f1all = (float*)((char*)d_ws + (8u << 20));          // 128 KB
    float* f2all = f1all + 16 * M_;                             // 128 KB
    u32*   maskp = (u32*)((char*)d_ws + (16u << 20));           // 8 MB
    k_prep<<<1024, 256, 0, stream>>>(h, Wp, ap, hbf, f1all, f2all);
    k_pack<<<2048, 256, 0, stream>>>(adjp, maskp);
    k_main<<<512, 256, 0, stream>>>(maskp, hbf, f1all, f2all, Wp, (float*)d_out);
}